// Round 5
// baseline (231.947 us; speedup 1.0000x reference)
//
#include <hip/hip_runtime.h>

// GPSA bf16-MFMA v5. B=64, N=300, C=256, H=8, hd=32.
// K0 prep: convert x/Wqk/Wv/Wproj -> bf16; gpos[h,i,j] = bf16(g_h * softmax_j(...)) [8,304,304]
// K2 gemm_qkv_mfma: x_bf @ W^T -> q(pre-scaled by 1/sqrt(32)),k,v bf16 [B,H,300,32]
// K3 attn_mfma: SINGLE fused tile loop. O = ps*(sum e*V) + (sum gpos*V):
//               dual accumulators Oe/Og, e consumed immediately (no e[19] array,
//               no gpos prefetch array -> ~45 live VGPRs, no spill; r3/r4 spilled
//               76 regs -> 48MB scratch traffic). gpos fed to MFMA as-is (bf16).
// K4 gemm_proj_mfma: o_bf @ Wproj^T + bias -> fp32 out

#define NSEQ 300
#define HEADS 8
#define HD 32

typedef short v8s __attribute__((ext_vector_type(8)));
typedef float v4f __attribute__((ext_vector_type(4)));
typedef unsigned int v4u __attribute__((ext_vector_type(4)));

__device__ __forceinline__ ushort f2bf(float f) {
    unsigned u = __float_as_uint(f);
    u = (u + 0x7FFFu + ((u >> 16) & 1u)) >> 16;   // RNE
    return (ushort)u;
}

// pack two fp32 -> packed bf16x2 (lo=a, hi=b) via v_perm
__device__ __forceinline__ unsigned pk2bf(float a, float b) {
    unsigned ua = __float_as_uint(a), ub = __float_as_uint(b);
    ua += 0x7FFFu + ((ua >> 16) & 1u);
    ub += 0x7FFFu + ((ub >> 16) & 1u);
    return __builtin_amdgcn_perm(ub, ua, 0x07060302);  // [ua.hi16 | ub.hi16]
}

// ---------------- K0: prep = convert + gated positional softmax ----------------
__global__ __launch_bounds__(256) void prep_kernel(
    const float* __restrict__ x, const float* __restrict__ Wqk,
    const float* __restrict__ Wv, const float* __restrict__ Wproj,
    const float* __restrict__ Wpos, const float* __restrict__ bpos,
    const float* __restrict__ gating,
    ushort* __restrict__ x_bf, ushort* __restrict__ wqkv_bf,
    ushort* __restrict__ wproj_bf, ushort* __restrict__ gpos)
{
    const int NX = 1228800, NQK = 32768, NV = 16384;
    int bid = blockIdx.x;
    if (bid < 5056) {
        int idx = bid * 256 + threadIdx.x;
        const float* src; ushort* dst;
        if (idx < NX)                { src = x + (size_t)idx * 4;              dst = x_bf + (size_t)idx * 4; }
        else if (idx < NX + NQK)     { int t = idx - NX;           src = Wqk + (size_t)t * 4;   dst = wqkv_bf + (size_t)t * 4; }
        else if (idx < NX + NQK + NV){ int t = idx - NX - NQK;     src = Wv + (size_t)t * 4;    dst = wqkv_bf + 131072 + (size_t)t * 4; }
        else                         { int t = idx - NX - NQK - NV; src = Wproj + (size_t)t * 4; dst = wproj_bf + (size_t)t * 4; }
        float4 v = *(const float4*)src;
        ushort4 o; o.x = f2bf(v.x); o.y = f2bf(v.y); o.z = f2bf(v.z); o.w = f2bf(v.w);
        *(ushort4*)dst = o;
        return;
    }
    int sub = bid - 5056;                       // 0..607
    int h = sub / 76;
    int i = (sub % 76) * 4 + (threadIdx.x >> 6);  // row 0..303
    int lane = threadIdx.x & 63;
    ushort* gr = gpos + ((size_t)h * 304 + i) * 304;
    if (i >= NSEQ) {
#pragma unroll
        for (int t = 0; t < 5; ++t) {
            int j = lane + 64 * t;
            if (j < 304) gr[j] = 0;
        }
        return;
    }
    float w0 = Wpos[h * 3 + 0], w2 = Wpos[h * 3 + 2], bb = bpos[h];
    float g = 1.f / (1.f + __expf(-gating[h]));
    float sv[5]; float m = -1e30f;
#pragma unroll
    for (int t = 0; t < 5; ++t) {
        int j = lane + 64 * t;
        float d = (float)(j - i);
        float lg = fmaf(w2, d * d, fmaf(w0, d, bb));
        sv[t] = (j < NSEQ) ? lg : -1e30f;       // logits +-7000: max-sub required
        m = fmaxf(m, sv[t]);
    }
#pragma unroll
    for (int off = 32; off > 0; off >>= 1) m = fmaxf(m, __shfl_xor(m, off));
    float sum = 0.f;
#pragma unroll
    for (int t = 0; t < 5; ++t) { sv[t] = __expf(sv[t] - m); sum += sv[t]; }
#pragma unroll
    for (int off = 32; off > 0; off >>= 1) sum += __shfl_xor(sum, off);
    float gi = g / sum;
#pragma unroll
    for (int t = 0; t < 5; ++t) {
        int j = lane + 64 * t;
        if (j < NSEQ) gr[j] = f2bf(sv[t] * gi);
        else if (j < 304) gr[j] = 0;
    }
}

// ---------------- K2: QKV GEMM, bf16 MFMA ----------------
__global__ __launch_bounds__(256) void gemm_qkv_mfma(
    const ushort* __restrict__ A, const ushort* __restrict__ Bw,
    ushort* __restrict__ qo, ushort* __restrict__ ko, ushort* __restrict__ vo)
{
    __shared__ ushort As[128 * 72];   // stride 72 (144B): 16B-mult, dword%32=4 -> 2-way (free)
    __shared__ ushort Bs[128 * 72];
    int tid = threadIdx.x;
    int wave = tid >> 6, lane = tid & 63, li = lane & 15, qd = lane >> 4;
    int row0 = blockIdx.y * 128, col0 = blockIdx.x * 128;
    int rh = wave >> 1, ch = wave & 1;

    v4f acc[4][4];
#pragma unroll
    for (int i = 0; i < 4; ++i)
#pragma unroll
        for (int j = 0; j < 4; ++j) acc[i][j] = (v4f){0.f, 0.f, 0.f, 0.f};

    for (int k0 = 0; k0 < 256; k0 += 64) {
#pragma unroll
        for (int s = 0; s < 4; ++s) {
            int c = s * 256 + tid;
            int r = c >> 3, k8 = (c & 7) * 8;
            *(uint4*)&As[r * 72 + k8] = *(const uint4*)(A + (size_t)(row0 + r) * 256 + k0 + k8);
            *(uint4*)&Bs[r * 72 + k8] = *(const uint4*)(Bw + (size_t)(col0 + r) * 256 + k0 + k8);
        }
        __syncthreads();
#pragma unroll
        for (int kc = 0; kc < 64; kc += 32) {
            v8s a[4], b[4];
#pragma unroll
            for (int mt = 0; mt < 4; ++mt)
                a[mt] = *(const v8s*)&As[(rh * 64 + mt * 16 + li) * 72 + kc + qd * 8];
#pragma unroll
            for (int nt = 0; nt < 4; ++nt)
                b[nt] = *(const v8s*)&Bs[(ch * 64 + nt * 16 + li) * 72 + kc + qd * 8];
#pragma unroll
            for (int mt = 0; mt < 4; ++mt)
#pragma unroll
                for (int nt = 0; nt < 4; ++nt)
                    acc[mt][nt] = __builtin_amdgcn_mfma_f32_16x16x32_bf16(a[mt], b[nt], acc[mt][nt], 0, 0, 0);
        }
        __syncthreads();
    }

    int reg3 = blockIdx.x >> 1;  // 0=q 1=k 2=v
    ushort* ob = (reg3 == 0) ? qo : (reg3 == 1) ? ko : vo;
    float sc = (reg3 == 0) ? 0.17677669529663687f : 1.0f;  // fold 1/sqrt(hd) into q
    int cb = (blockIdx.x & 1) * 128 + ch * 64;
#pragma unroll
    for (int mt = 0; mt < 4; ++mt)
#pragma unroll
        for (int nt = 0; nt < 4; ++nt) {
            int col = cb + nt * 16 + li;
            int hh = col >> 5, dd = col & 31;
#pragma unroll
            for (int r = 0; r < 4; ++r) {
                unsigned row = row0 + rh * 64 + mt * 16 + qd * 4 + r;
                unsigned bb = row / 300u;
                unsigned nn = row - bb * 300u;
                ob[(((size_t)bb * 8 + hh) * 300 + nn) * 32 + dd] = f2bf(acc[mt][nt][r] * sc);
            }
        }
}

// ---------------- K3: fused attention, single-loop dual-accumulator ----------------
// S^T = mfma(A=K_tile, B=Q_tile): lane li = query row i, regs (qd*4+r) = key col j.
// Per tile: e = exp(s) consumed immediately into Oe += e*V; Og += gpos*V (gpos is
// already packed bf16 -> direct A-operand). Epilogue: O = psr*Oe + Og, where
// psr[r] = shfl(ps, qd*4+r) re-aligns the per-row 1/esum to the C-layout rows.
__global__ __launch_bounds__(256, 2) void attn_mfma(
    const ushort* __restrict__ qg, const ushort* __restrict__ kg,
    const ushort* __restrict__ vg, const ushort* __restrict__ gpos,
    const float* __restrict__ gating, ushort* __restrict__ og)
{
    __shared__ ushort Ks[304 * 40];    // [seq][k] stride 40 (80B)
    __shared__ ushort Vt[32 * 328];    // [dim][seq] stride 328 (656B), seq 300..327 zero

    int bh = blockIdx.x, b = bh >> 3, h = bh & 7;
    int tid = threadIdx.x, wave = tid >> 6, lane = tid & 63, li = lane & 15, qd = lane >> 4;
    const ushort* kb = kg + (size_t)bh * 9600;
    const ushort* vb = vg + (size_t)bh * 9600;

    for (int c = tid; c < 1200; c += 256) {        // K: 300 rows x 4 u8-chunks
        int r = c >> 2, k8 = (c & 3) * 8;
        *(uint4*)&Ks[r * 40 + k8] = *(const uint4*)(kb + r * 32 + k8);
    }
    for (int c = tid; c < 2400; c += 256) {        // V transpose: 300 x 8 u4-chunks
        int sq = c >> 3, d4 = (c & 7) * 4;
        ushort4 t = *(const ushort4*)(vb + sq * 32 + d4);
        Vt[(d4 + 0) * 328 + sq] = t.x;
        Vt[(d4 + 1) * 328 + sq] = t.y;
        Vt[(d4 + 2) * 328 + sq] = t.z;
        Vt[(d4 + 3) * 328 + sq] = t.w;
    }
    for (int c = tid; c < 896; c += 256) {         // Vt seq pad 300..327 -> 0
        int d = c & 31, s = c >> 5;
        Vt[d * 328 + 300 + s] = 0;
    }
    float g = 1.f / (1.f + __expf(-gating[h]));
    float omg = 1.f - g;
    __syncthreads();

    for (int rg = wave; rg < 19; rg += 4) {
        int i0 = rg * 16;
        // Q as B-operand: lane li holds Q row (i0+li); rows>=300 read into adjacent
        // k_bf region (valid memory, finite, masked at store)
        v8s bq = *(const v8s*)(qg + (size_t)bh * 9600 + (i0 + li) * 32 + qd * 8);
        const ushort* gp = gpos + ((size_t)h * 304 + (i0 + li)) * 304;

        v4f Oe0 = {0.f, 0.f, 0.f, 0.f}, Oe1 = {0.f, 0.f, 0.f, 0.f};
        v4f Og0 = {0.f, 0.f, 0.f, 0.f}, Og1 = {0.f, 0.f, 0.f, 0.f};
        float esum = 0.f;
#pragma unroll
        for (int nt = 0; nt < 19; ++nt) {
            uint2 gpl = *(const uint2*)(gp + nt * 16 + qd * 4);   // bf16x4, pad cols are 0
            v8s ak = *(const v8s*)&Ks[(nt * 16 + li) * 40 + qd * 8];
            v4f s = __builtin_amdgcn_mfma_f32_16x16x32_bf16(ak, bq, (v4f){0.f, 0.f, 0.f, 0.f}, 0, 0, 0);
            float e0 = __expf(s[0]);               // scale folded into q
            float e1 = __expf(s[1]);
            float e2 = __expf(s[2]);
            float e3 = __expf(s[3]);
            if (nt == 18 && qd == 3) { e0 = e1 = e2 = e3 = 0.f; }  // j >= 300 (stale Ks rows)
            esum += (e0 + e1) + (e2 + e3);
            v8s ae = __builtin_bit_cast(v8s, (v4u){pk2bf(e0, e1), pk2bf(e2, e3), 0u, 0u});
            v8s ag = __builtin_bit_cast(v8s, (v4u){gpl.x, gpl.y, 0u, 0u});
            uint2 v0 = *(const uint2*)&Vt[li * 328 + nt * 16 + qd * 4];
            uint2 v1 = *(const uint2*)&Vt[(16 + li) * 328 + nt * 16 + qd * 4];
            v8s b0 = __builtin_bit_cast(v8s, (v4u){v0.x, v0.y, 0u, 0u});
            v8s b1 = __builtin_bit_cast(v8s, (v4u){v1.x, v1.y, 0u, 0u});
            Oe0 = __builtin_amdgcn_mfma_f32_16x16x32_bf16(ae, b0, Oe0, 0, 0, 0);
            Oe1 = __builtin_amdgcn_mfma_f32_16x16x32_bf16(ae, b1, Oe1, 0, 0, 0);
            Og0 = __builtin_amdgcn_mfma_f32_16x16x32_bf16(ag, b0, Og0, 0, 0, 0);
            Og1 = __builtin_amdgcn_mfma_f32_16x16x32_bf16(ag, b1, Og1, 0, 0, 0);
        }
        esum += __shfl_xor(esum, 16);
        esum += __shfl_xor(esum, 32);              // full row sum for query i0+li
        float ps = omg / esum;                     // (skip /attn.sum: it's 1 +- 1e-6)
        // re-align ps (row i0+li) to C-layout rows (i0+qd*4+r)
        float psr[4];
#pragma unroll
        for (int r = 0; r < 4; ++r) psr[r] = __shfl(ps, qd * 4 + r);
#pragma unroll
        for (int r = 0; r < 4; ++r) {
            int row = i0 + qd * 4 + r;
            if (row < NSEQ) {
                size_t base = ((size_t)b * NSEQ + row) * 256 + h * 32 + li;
                og[base] = f2bf(fmaf(psr[r], Oe0[r], Og0[r]));
                og[base + 16] = f2bf(fmaf(psr[r], Oe1[r], Og1[r]));
            }
        }
    }
}

// ---------------- K4: output projection, bf16 MFMA + fp32 bias ----------------
__global__ __launch_bounds__(256) void gemm_proj_mfma(
    const ushort* __restrict__ A, const ushort* __restrict__ Bw,
    const float* __restrict__ bias, float* __restrict__ out)
{
    __shared__ ushort As[128 * 72];
    __shared__ ushort Bs[128 * 72];
    int tid = threadIdx.x;
    int wave = tid >> 6, lane = tid & 63, li = lane & 15, qd = lane >> 4;
    int row0 = blockIdx.y * 128, col0 = blockIdx.x * 128;
    int rh = wave >> 1, ch = wave & 1;

    v4f acc[4][4];
#pragma unroll
    for (int i = 0; i < 4; ++i)
#pragma unroll
        for (int j = 0; j < 4; ++j) acc[i][j] = (v4f){0.f, 0.f, 0.f, 0.f};

    for (int k0 = 0; k0 < 256; k0 += 64) {
#pragma unroll
        for (int s = 0; s < 4; ++s) {
            int c = s * 256 + tid;
            int r = c >> 3, k8 = (c & 7) * 8;
            *(uint4*)&As[r * 72 + k8] = *(const uint4*)(A + (size_t)(row0 + r) * 256 + k0 + k8);
            *(uint4*)&Bs[r * 72 + k8] = *(const uint4*)(Bw + (size_t)(col0 + r) * 256 + k0 + k8);
        }
        __syncthreads();
#pragma unroll
        for (int kc = 0; kc < 64; kc += 32) {
            v8s a[4], b[4];
#pragma unroll
            for (int mt = 0; mt < 4; ++mt)
                a[mt] = *(const v8s*)&As[(rh * 64 + mt * 16 + li) * 72 + kc + qd * 8];
#pragma unroll
            for (int nt = 0; nt < 4; ++nt)
                b[nt] = *(const v8s*)&Bs[(ch * 64 + nt * 16 + li) * 72 + kc + qd * 8];
#pragma unroll
            for (int mt = 0; mt < 4; ++mt)
#pragma unroll
                for (int nt = 0; nt < 4; ++nt)
                    acc[mt][nt] = __builtin_amdgcn_mfma_f32_16x16x32_bf16(a[mt], b[nt], acc[mt][nt], 0, 0, 0);
        }
        __syncthreads();
    }

#pragma unroll
    for (int mt = 0; mt < 4; ++mt)
#pragma unroll
        for (int nt = 0; nt < 4; ++nt) {
            int col = col0 + ch * 64 + nt * 16 + li;
            float bv = bias[col];
#pragma unroll
            for (int r = 0; r < 4; ++r) {
                int row = row0 + rh * 64 + mt * 16 + qd * 4 + r;
                out[(size_t)row * 256 + col] = acc[mt][nt][r] + bv;
            }
        }
}

extern "C" void kernel_launch(void* const* d_in, const int* in_sizes, int n_in,
                              void* d_out, int out_size, void* d_ws, size_t ws_size,
                              hipStream_t stream) {
    const float* x      = (const float*)d_in[0];
    const float* Wqk    = (const float*)d_in[1];
    const float* Wv     = (const float*)d_in[2];
    const float* Wpos   = (const float*)d_in[3];
    const float* bpos   = (const float*)d_in[4];
    const float* Wproj  = (const float*)d_in[5];
    const float* bproj  = (const float*)d_in[6];
    const float* gating = (const float*)d_in[7];
    float* out = (float*)d_out;

    ushort* gpos     = (ushort*)d_ws;             // 8*304*304 = 739,328
    ushort* x_bf     = gpos + 739328;             // 4,915,200
    ushort* wqkv_bf  = x_bf + 4915200;            // 196,608 (Wqk 0..511, Wv 512..767)
    ushort* wproj_bf = wqkv_bf + 196608;          // 65,536
    ushort* q_bf     = wproj_bf + 65536;          // 4,915,200 each
    ushort* k_bf     = q_bf + 4915200;
    ushort* v_bf     = k_bf + 4915200;
    ushort* o_bf     = v_bf + 4915200;

    prep_kernel<<<5664, 256, 0, stream>>>(x, Wqk, Wv, Wproj, Wpos, bpos, gating,
                                          x_bf, wqkv_bf, wproj_bf, gpos);
    gemm_qkv_mfma<<<dim3(6, 150), 256, 0, stream>>>(x_bf, wqkv_bf, q_bf, k_bf, v_bf);
    attn_mfma<<<dim3(64 * HEADS), 256, 0, stream>>>(q_bf, k_bf, v_bf, gpos, gating, o_bf);
    gemm_proj_mfma<<<dim3(2, 150), 256, 0, stream>>>(o_bf, wproj_bf, bproj, out);
}

// Round 6
// 161.216 us; speedup vs baseline: 1.4387x; 1.4387x over previous
//
#include <hip/hip_runtime.h>

// GPSA bf16-MFMA v6. B=64, N=300, C=256, H=8, hd=32.
// K0 prep: convert x/Wqk/Wv/Wproj -> bf16; gpos[h,i,j] = bf16(g_h * softmax_j(...)) [8,304,304]
// K2 gemm_qkv_mfma: x_bf @ W^T -> q(pre-scaled by 1/sqrt(32)),k,v bf16 [B,H,300,32]
// K3 attn_mfma: single fused tile loop, O = ps*(sum e*V) + (sum gpos*V).
//               *** tile loop is #pragma unroll 1 *** — r3/r4/r5 all spilled
//               (57..119 MB scratch WRITE_SIZE) because the unrolled 19-iter loop
//               let the scheduler hoist ~19 independent S-MFMAs + 57 loads ahead
//               of the serialized accumulator chains (~190 in-flight regs).
// K4 gemm_proj_mfma: o_bf @ Wproj^T + bias -> fp32 out

#define NSEQ 300
#define HEADS 8
#define HD 32

typedef short v8s __attribute__((ext_vector_type(8)));
typedef float v4f __attribute__((ext_vector_type(4)));
typedef unsigned int v4u __attribute__((ext_vector_type(4)));

__device__ __forceinline__ ushort f2bf(float f) {
    unsigned u = __float_as_uint(f);
    u = (u + 0x7FFFu + ((u >> 16) & 1u)) >> 16;   // RNE
    return (ushort)u;
}

// pack two fp32 -> packed bf16x2 (lo=a, hi=b) via v_perm
__device__ __forceinline__ unsigned pk2bf(float a, float b) {
    unsigned ua = __float_as_uint(a), ub = __float_as_uint(b);
    ua += 0x7FFFu + ((ua >> 16) & 1u);
    ub += 0x7FFFu + ((ub >> 16) & 1u);
    return __builtin_amdgcn_perm(ub, ua, 0x07060302);  // [ua.hi16 | ub.hi16]
}

// ---------------- K0: prep = convert + gated positional softmax ----------------
__global__ __launch_bounds__(256) void prep_kernel(
    const float* __restrict__ x, const float* __restrict__ Wqk,
    const float* __restrict__ Wv, const float* __restrict__ Wproj,
    const float* __restrict__ Wpos, const float* __restrict__ bpos,
    const float* __restrict__ gating,
    ushort* __restrict__ x_bf, ushort* __restrict__ wqkv_bf,
    ushort* __restrict__ wproj_bf, ushort* __restrict__ gpos)
{
    const int NX = 1228800, NQK = 32768, NV = 16384;
    int bid = blockIdx.x;
    if (bid < 5056) {
        int idx = bid * 256 + threadIdx.x;
        const float* src; ushort* dst;
        if (idx < NX)                { src = x + (size_t)idx * 4;              dst = x_bf + (size_t)idx * 4; }
        else if (idx < NX + NQK)     { int t = idx - NX;           src = Wqk + (size_t)t * 4;   dst = wqkv_bf + (size_t)t * 4; }
        else if (idx < NX + NQK + NV){ int t = idx - NX - NQK;     src = Wv + (size_t)t * 4;    dst = wqkv_bf + 131072 + (size_t)t * 4; }
        else                         { int t = idx - NX - NQK - NV; src = Wproj + (size_t)t * 4; dst = wproj_bf + (size_t)t * 4; }
        float4 v = *(const float4*)src;
        ushort4 o; o.x = f2bf(v.x); o.y = f2bf(v.y); o.z = f2bf(v.z); o.w = f2bf(v.w);
        *(ushort4*)dst = o;
        return;
    }
    int sub = bid - 5056;                       // 0..607
    int h = sub / 76;
    int i = (sub % 76) * 4 + (threadIdx.x >> 6);  // row 0..303
    int lane = threadIdx.x & 63;
    ushort* gr = gpos + ((size_t)h * 304 + i) * 304;
    if (i >= NSEQ) {
#pragma unroll
        for (int t = 0; t < 5; ++t) {
            int j = lane + 64 * t;
            if (j < 304) gr[j] = 0;
        }
        return;
    }
    float w0 = Wpos[h * 3 + 0], w2 = Wpos[h * 3 + 2], bb = bpos[h];
    float g = 1.f / (1.f + __expf(-gating[h]));
    float sv[5]; float m = -1e30f;
#pragma unroll
    for (int t = 0; t < 5; ++t) {
        int j = lane + 64 * t;
        float d = (float)(j - i);
        float lg = fmaf(w2, d * d, fmaf(w0, d, bb));
        sv[t] = (j < NSEQ) ? lg : -1e30f;       // logits +-7000: max-sub required
        m = fmaxf(m, sv[t]);
    }
#pragma unroll
    for (int off = 32; off > 0; off >>= 1) m = fmaxf(m, __shfl_xor(m, off));
    float sum = 0.f;
#pragma unroll
    for (int t = 0; t < 5; ++t) { sv[t] = __expf(sv[t] - m); sum += sv[t]; }
#pragma unroll
    for (int off = 32; off > 0; off >>= 1) sum += __shfl_xor(sum, off);
    float gi = g / sum;
#pragma unroll
    for (int t = 0; t < 5; ++t) {
        int j = lane + 64 * t;
        if (j < NSEQ) gr[j] = f2bf(sv[t] * gi);
        else if (j < 304) gr[j] = 0;
    }
}

// ---------------- K2: QKV GEMM, bf16 MFMA ----------------
__global__ __launch_bounds__(256) void gemm_qkv_mfma(
    const ushort* __restrict__ A, const ushort* __restrict__ Bw,
    ushort* __restrict__ qo, ushort* __restrict__ ko, ushort* __restrict__ vo)
{
    __shared__ ushort As[128 * 72];   // stride 72 (144B): 16B-mult, dword%32=4 -> 2-way (free)
    __shared__ ushort Bs[128 * 72];
    int tid = threadIdx.x;
    int wave = tid >> 6, lane = tid & 63, li = lane & 15, qd = lane >> 4;
    int row0 = blockIdx.y * 128, col0 = blockIdx.x * 128;
    int rh = wave >> 1, ch = wave & 1;

    v4f acc[4][4];
#pragma unroll
    for (int i = 0; i < 4; ++i)
#pragma unroll
        for (int j = 0; j < 4; ++j) acc[i][j] = (v4f){0.f, 0.f, 0.f, 0.f};

    for (int k0 = 0; k0 < 256; k0 += 64) {
#pragma unroll
        for (int s = 0; s < 4; ++s) {
            int c = s * 256 + tid;
            int r = c >> 3, k8 = (c & 7) * 8;
            *(uint4*)&As[r * 72 + k8] = *(const uint4*)(A + (size_t)(row0 + r) * 256 + k0 + k8);
            *(uint4*)&Bs[r * 72 + k8] = *(const uint4*)(Bw + (size_t)(col0 + r) * 256 + k0 + k8);
        }
        __syncthreads();
#pragma unroll
        for (int kc = 0; kc < 64; kc += 32) {
            v8s a[4], b[4];
#pragma unroll
            for (int mt = 0; mt < 4; ++mt)
                a[mt] = *(const v8s*)&As[(rh * 64 + mt * 16 + li) * 72 + kc + qd * 8];
#pragma unroll
            for (int nt = 0; nt < 4; ++nt)
                b[nt] = *(const v8s*)&Bs[(ch * 64 + nt * 16 + li) * 72 + kc + qd * 8];
#pragma unroll
            for (int mt = 0; mt < 4; ++mt)
#pragma unroll
                for (int nt = 0; nt < 4; ++nt)
                    acc[mt][nt] = __builtin_amdgcn_mfma_f32_16x16x32_bf16(a[mt], b[nt], acc[mt][nt], 0, 0, 0);
        }
        __syncthreads();
    }

    int reg3 = blockIdx.x >> 1;  // 0=q 1=k 2=v
    ushort* ob = (reg3 == 0) ? qo : (reg3 == 1) ? ko : vo;
    float sc = (reg3 == 0) ? 0.17677669529663687f : 1.0f;  // fold 1/sqrt(hd) into q
    int cb = (blockIdx.x & 1) * 128 + ch * 64;
#pragma unroll
    for (int mt = 0; mt < 4; ++mt)
#pragma unroll
        for (int nt = 0; nt < 4; ++nt) {
            int col = cb + nt * 16 + li;
            int hh = col >> 5, dd = col & 31;
#pragma unroll
            for (int r = 0; r < 4; ++r) {
                unsigned row = row0 + rh * 64 + mt * 16 + qd * 4 + r;
                unsigned bb = row / 300u;
                unsigned nn = row - bb * 300u;
                ob[(((size_t)bb * 8 + hh) * 300 + nn) * 32 + dd] = f2bf(acc[mt][nt][r] * sc);
            }
        }
}

// ---------------- K3: fused attention, single-loop dual-accumulator, ROLLED ----------------
// S^T = mfma(A=K_tile, B=Q_tile): lane li = query row i, regs (qd*4+r) = key col j.
// Per tile: e = exp(s) consumed immediately into Oe += e*V; Og += gpos*V.
// Epilogue: O = psr*Oe + Og with psr[r] = shfl(ps, qd*4+r).
__global__ __launch_bounds__(256, 2) void attn_mfma(
    const ushort* __restrict__ qg, const ushort* __restrict__ kg,
    const ushort* __restrict__ vg, const ushort* __restrict__ gpos,
    const float* __restrict__ gating, ushort* __restrict__ og)
{
    __shared__ ushort Ks[304 * 40];    // [seq][k] stride 40 (80B)
    __shared__ ushort Vt[32 * 328];    // [dim][seq] stride 328 (656B), seq 300..327 zero

    int bh = blockIdx.x, b = bh >> 3, h = bh & 7;
    int tid = threadIdx.x, wave = tid >> 6, lane = tid & 63, li = lane & 15, qd = lane >> 4;
    const ushort* kb = kg + (size_t)bh * 9600;
    const ushort* vb = vg + (size_t)bh * 9600;

    for (int c = tid; c < 1200; c += 256) {        // K: 300 rows x 4 u8-chunks
        int r = c >> 2, k8 = (c & 3) * 8;
        *(uint4*)&Ks[r * 40 + k8] = *(const uint4*)(kb + r * 32 + k8);
    }
    for (int c = tid; c < 2400; c += 256) {        // V transpose: 300 x 8 u4-chunks
        int sq = c >> 3, d4 = (c & 7) * 4;
        ushort4 t = *(const ushort4*)(vb + sq * 32 + d4);
        Vt[(d4 + 0) * 328 + sq] = t.x;
        Vt[(d4 + 1) * 328 + sq] = t.y;
        Vt[(d4 + 2) * 328 + sq] = t.z;
        Vt[(d4 + 3) * 328 + sq] = t.w;
    }
    for (int c = tid; c < 896; c += 256) {         // Vt seq pad 300..327 -> 0
        int d = c & 31, s = c >> 5;
        Vt[d * 328 + 300 + s] = 0;
    }
    float g = 1.f / (1.f + __expf(-gating[h]));
    float omg = 1.f - g;
    __syncthreads();

    const ushort* ksp0 = &Ks[li * 40 + qd * 8];
    const ushort* vtp0 = &Vt[li * 328 + qd * 4];
    const ushort* vtp1 = &Vt[(16 + li) * 328 + qd * 4];

    for (int rg = wave; rg < 19; rg += 4) {
        int i0 = rg * 16;
        // Q as B-operand: lane li holds Q row (i0+li); rows>=300 read into adjacent
        // k_bf region (valid memory, finite, masked at store)
        v8s bq = *(const v8s*)(qg + (size_t)bh * 9600 + (i0 + li) * 32 + qd * 8);
        const ushort* gp = gpos + ((size_t)h * 304 + (i0 + li)) * 304 + qd * 4;

        v4f Oe0 = {0.f, 0.f, 0.f, 0.f}, Oe1 = {0.f, 0.f, 0.f, 0.f};
        v4f Og0 = {0.f, 0.f, 0.f, 0.f}, Og1 = {0.f, 0.f, 0.f, 0.f};
        float esum = 0.f;
#pragma unroll 1
        for (int nt = 0; nt < 19; ++nt) {      // ROLLED: caps in-flight regs (~1 iter)
            uint2 gpl = *(const uint2*)(gp + nt * 16);        // bf16x4, pad cols 0
            v8s ak = *(const v8s*)(ksp0 + nt * 640);          // 16 rows x stride 40
            v4f s = __builtin_amdgcn_mfma_f32_16x16x32_bf16(ak, bq, (v4f){0.f, 0.f, 0.f, 0.f}, 0, 0, 0);
            float e0 = __expf(s[0]);               // scale folded into q
            float e1 = __expf(s[1]);
            float e2 = __expf(s[2]);
            float e3 = __expf(s[3]);
            if (nt == 18 && qd == 3) { e0 = e1 = e2 = e3 = 0.f; }  // j >= 300 (stale Ks rows)
            esum += (e0 + e1) + (e2 + e3);
            v8s ae = __builtin_bit_cast(v8s, (v4u){pk2bf(e0, e1), pk2bf(e2, e3), 0u, 0u});
            v8s ag = __builtin_bit_cast(v8s, (v4u){gpl.x, gpl.y, 0u, 0u});
            uint2 v0 = *(const uint2*)(vtp0 + nt * 16);
            uint2 v1 = *(const uint2*)(vtp1 + nt * 16);
            v8s b0 = __builtin_bit_cast(v8s, (v4u){v0.x, v0.y, 0u, 0u});
            v8s b1 = __builtin_bit_cast(v8s, (v4u){v1.x, v1.y, 0u, 0u});
            Oe0 = __builtin_amdgcn_mfma_f32_16x16x32_bf16(ae, b0, Oe0, 0, 0, 0);
            Oe1 = __builtin_amdgcn_mfma_f32_16x16x32_bf16(ae, b1, Oe1, 0, 0, 0);
            Og0 = __builtin_amdgcn_mfma_f32_16x16x32_bf16(ag, b0, Og0, 0, 0, 0);
            Og1 = __builtin_amdgcn_mfma_f32_16x16x32_bf16(ag, b1, Og1, 0, 0, 0);
        }
        esum += __shfl_xor(esum, 16);
        esum += __shfl_xor(esum, 32);              // full row sum for query i0+li
        float ps = omg / esum;                     // (skip /attn.sum: it's 1 +- 1e-6)
        // re-align ps (row i0+li) to C-layout rows (i0+qd*4+r)
        float psr[4];
#pragma unroll
        for (int r = 0; r < 4; ++r) psr[r] = __shfl(ps, qd * 4 + r);
#pragma unroll
        for (int r = 0; r < 4; ++r) {
            int row = i0 + qd * 4 + r;
            if (row < NSEQ) {
                size_t base = ((size_t)b * NSEQ + row) * 256 + h * 32 + li;
                og[base] = f2bf(fmaf(psr[r], Oe0[r], Og0[r]));
                og[base + 16] = f2bf(fmaf(psr[r], Oe1[r], Og1[r]));
            }
        }
    }
}

// ---------------- K4: output projection, bf16 MFMA + fp32 bias ----------------
__global__ __launch_bounds__(256) void gemm_proj_mfma(
    const ushort* __restrict__ A, const ushort* __restrict__ Bw,
    const float* __restrict__ bias, float* __restrict__ out)
{
    __shared__ ushort As[128 * 72];
    __shared__ ushort Bs[128 * 72];
    int tid = threadIdx.x;
    int wave = tid >> 6, lane = tid & 63, li = lane & 15, qd = lane >> 4;
    int row0 = blockIdx.y * 128, col0 = blockIdx.x * 128;
    int rh = wave >> 1, ch = wave & 1;

    v4f acc[4][4];
#pragma unroll
    for (int i = 0; i < 4; ++i)
#pragma unroll
        for (int j = 0; j < 4; ++j) acc[i][j] = (v4f){0.f, 0.f, 0.f, 0.f};

    for (int k0 = 0; k0 < 256; k0 += 64) {
#pragma unroll
        for (int s = 0; s < 4; ++s) {
            int c = s * 256 + tid;
            int r = c >> 3, k8 = (c & 7) * 8;
            *(uint4*)&As[r * 72 + k8] = *(const uint4*)(A + (size_t)(row0 + r) * 256 + k0 + k8);
            *(uint4*)&Bs[r * 72 + k8] = *(const uint4*)(Bw + (size_t)(col0 + r) * 256 + k0 + k8);
        }
        __syncthreads();
#pragma unroll
        for (int kc = 0; kc < 64; kc += 32) {
            v8s a[4], b[4];
#pragma unroll
            for (int mt = 0; mt < 4; ++mt)
                a[mt] = *(const v8s*)&As[(rh * 64 + mt * 16 + li) * 72 + kc + qd * 8];
#pragma unroll
            for (int nt = 0; nt < 4; ++nt)
                b[nt] = *(const v8s*)&Bs[(ch * 64 + nt * 16 + li) * 72 + kc + qd * 8];
#pragma unroll
            for (int mt = 0; mt < 4; ++mt)
#pragma unroll
                for (int nt = 0; nt < 4; ++nt)
                    acc[mt][nt] = __builtin_amdgcn_mfma_f32_16x16x32_bf16(a[mt], b[nt], acc[mt][nt], 0, 0, 0);
        }
        __syncthreads();
    }

#pragma unroll
    for (int mt = 0; mt < 4; ++mt)
#pragma unroll
        for (int nt = 0; nt < 4; ++nt) {
            int col = col0 + ch * 64 + nt * 16 + li;
            float bv = bias[col];
#pragma unroll
            for (int r = 0; r < 4; ++r) {
                int row = row0 + rh * 64 + mt * 16 + qd * 4 + r;
                out[(size_t)row * 256 + col] = acc[mt][nt][r] + bv;
            }
        }
}

extern "C" void kernel_launch(void* const* d_in, const int* in_sizes, int n_in,
                              void* d_out, int out_size, void* d_ws, size_t ws_size,
                              hipStream_t stream) {
    const float* x      = (const float*)d_in[0];
    const float* Wqk    = (const float*)d_in[1];
    const float* Wv     = (const float*)d_in[2];
    const float* Wpos   = (const float*)d_in[3];
    const float* bpos   = (const float*)d_in[4];
    const float* Wproj  = (const float*)d_in[5];
    const float* bproj  = (const float*)d_in[6];
    const float* gating = (const float*)d_in[7];
    float* out = (float*)d_out;

    ushort* gpos     = (ushort*)d_ws;             // 8*304*304 = 739,328
    ushort* x_bf     = gpos + 739328;             // 4,915,200
    ushort* wqkv_bf  = x_bf + 4915200;            // 196,608 (Wqk 0..511, Wv 512..767)
    ushort* wproj_bf = wqkv_bf + 196608;          // 65,536
    ushort* q_bf     = wproj_bf + 65536;          // 4,915,200 each
    ushort* k_bf     = q_bf + 4915200;
    ushort* v_bf     = k_bf + 4915200;
    ushort* o_bf     = v_bf + 4915200;

    prep_kernel<<<5664, 256, 0, stream>>>(x, Wqk, Wv, Wproj, Wpos, bpos, gating,
                                          x_bf, wqkv_bf, wproj_bf, gpos);
    gemm_qkv_mfma<<<dim3(6, 150), 256, 0, stream>>>(x_bf, wqkv_bf, q_bf, k_bf, v_bf);
    attn_mfma<<<dim3(64 * HEADS), 256, 0, stream>>>(q_bf, k_bf, v_bf, gpos, gating, o_bf);
    gemm_proj_mfma<<<dim3(2, 150), 256, 0, stream>>>(o_bf, wproj_bf, bproj, out);
}

// Round 7
// 159.923 us; speedup vs baseline: 1.4504x; 1.0081x over previous
//
#include <hip/hip_runtime.h>

// GPSA bf16-MFMA v7. B=64, N=300, C=256, H=8, hd=32.
// K0 prep: convert x/Wqk/Wv/Wproj -> bf16; gpos[h,i,j] = bf16(g_h * softmax_j(...)) [8,304,304]
// K2 gemm_qkv_mfma: x_bf @ W^T -> q(pre-scaled by 1/sqrt(32)),k,v bf16 [B,H,300,32]
// K3 attn_mfma: rolled tile loop (no spill) + MANUAL SOFTWARE PIPELINE:
//               next-iter ak/v + S-MFMA issued before current exp/PV; gpos global
//               load prefetched 2 iters ahead (L2 ~200cyc). r6's unpipelined rolled
//               loop exposed that latency serially each of 95 iterations.
// K4 gemm_proj_mfma: BM=64 (600 blocks; 300 left half the CUs idle), + bias -> fp32

#define NSEQ 300
#define HEADS 8
#define HD 32

typedef short v8s __attribute__((ext_vector_type(8)));
typedef float v4f __attribute__((ext_vector_type(4)));
typedef unsigned int v4u __attribute__((ext_vector_type(4)));

__device__ __forceinline__ ushort f2bf(float f) {
    unsigned u = __float_as_uint(f);
    u = (u + 0x7FFFu + ((u >> 16) & 1u)) >> 16;   // RNE
    return (ushort)u;
}

// pack two fp32 -> packed bf16x2 (lo=a, hi=b) via v_perm
__device__ __forceinline__ unsigned pk2bf(float a, float b) {
    unsigned ua = __float_as_uint(a), ub = __float_as_uint(b);
    ua += 0x7FFFu + ((ua >> 16) & 1u);
    ub += 0x7FFFu + ((ub >> 16) & 1u);
    return __builtin_amdgcn_perm(ub, ua, 0x07060302);  // [ua.hi16 | ub.hi16]
}

// ---------------- K0: prep = convert + gated positional softmax ----------------
__global__ __launch_bounds__(256) void prep_kernel(
    const float* __restrict__ x, const float* __restrict__ Wqk,
    const float* __restrict__ Wv, const float* __restrict__ Wproj,
    const float* __restrict__ Wpos, const float* __restrict__ bpos,
    const float* __restrict__ gating,
    ushort* __restrict__ x_bf, ushort* __restrict__ wqkv_bf,
    ushort* __restrict__ wproj_bf, ushort* __restrict__ gpos)
{
    const int NX = 1228800, NQK = 32768, NV = 16384;
    int bid = blockIdx.x;
    if (bid < 5056) {
        int idx = bid * 256 + threadIdx.x;
        const float* src; ushort* dst;
        if (idx < NX)                { src = x + (size_t)idx * 4;              dst = x_bf + (size_t)idx * 4; }
        else if (idx < NX + NQK)     { int t = idx - NX;           src = Wqk + (size_t)t * 4;   dst = wqkv_bf + (size_t)t * 4; }
        else if (idx < NX + NQK + NV){ int t = idx - NX - NQK;     src = Wv + (size_t)t * 4;    dst = wqkv_bf + 131072 + (size_t)t * 4; }
        else                         { int t = idx - NX - NQK - NV; src = Wproj + (size_t)t * 4; dst = wproj_bf + (size_t)t * 4; }
        float4 v = *(const float4*)src;
        ushort4 o; o.x = f2bf(v.x); o.y = f2bf(v.y); o.z = f2bf(v.z); o.w = f2bf(v.w);
        *(ushort4*)dst = o;
        return;
    }
    int sub = bid - 5056;                       // 0..607
    int h = sub / 76;
    int i = (sub % 76) * 4 + (threadIdx.x >> 6);  // row 0..303
    int lane = threadIdx.x & 63;
    ushort* gr = gpos + ((size_t)h * 304 + i) * 304;
    if (i >= NSEQ) {
#pragma unroll
        for (int t = 0; t < 5; ++t) {
            int j = lane + 64 * t;
            if (j < 304) gr[j] = 0;
        }
        return;
    }
    float w0 = Wpos[h * 3 + 0], w2 = Wpos[h * 3 + 2], bb = bpos[h];
    float g = 1.f / (1.f + __expf(-gating[h]));
    float sv[5]; float m = -1e30f;
#pragma unroll
    for (int t = 0; t < 5; ++t) {
        int j = lane + 64 * t;
        float d = (float)(j - i);
        float lg = fmaf(w2, d * d, fmaf(w0, d, bb));
        sv[t] = (j < NSEQ) ? lg : -1e30f;       // logits +-7000: max-sub required
        m = fmaxf(m, sv[t]);
    }
#pragma unroll
    for (int off = 32; off > 0; off >>= 1) m = fmaxf(m, __shfl_xor(m, off));
    float sum = 0.f;
#pragma unroll
    for (int t = 0; t < 5; ++t) { sv[t] = __expf(sv[t] - m); sum += sv[t]; }
#pragma unroll
    for (int off = 32; off > 0; off >>= 1) sum += __shfl_xor(sum, off);
    float gi = g / sum;
#pragma unroll
    for (int t = 0; t < 5; ++t) {
        int j = lane + 64 * t;
        if (j < NSEQ) gr[j] = f2bf(sv[t] * gi);
        else if (j < 304) gr[j] = 0;
    }
}

// ---------------- K2: QKV GEMM, bf16 MFMA ----------------
__global__ __launch_bounds__(256) void gemm_qkv_mfma(
    const ushort* __restrict__ A, const ushort* __restrict__ Bw,
    ushort* __restrict__ qo, ushort* __restrict__ ko, ushort* __restrict__ vo)
{
    __shared__ ushort As[128 * 72];   // stride 72 (144B): 16B-mult, dword%32=4 -> 2-way (free)
    __shared__ ushort Bs[128 * 72];
    int tid = threadIdx.x;
    int wave = tid >> 6, lane = tid & 63, li = lane & 15, qd = lane >> 4;
    int row0 = blockIdx.y * 128, col0 = blockIdx.x * 128;
    int rh = wave >> 1, ch = wave & 1;

    v4f acc[4][4];
#pragma unroll
    for (int i = 0; i < 4; ++i)
#pragma unroll
        for (int j = 0; j < 4; ++j) acc[i][j] = (v4f){0.f, 0.f, 0.f, 0.f};

    for (int k0 = 0; k0 < 256; k0 += 64) {
#pragma unroll
        for (int s = 0; s < 4; ++s) {
            int c = s * 256 + tid;
            int r = c >> 3, k8 = (c & 7) * 8;
            *(uint4*)&As[r * 72 + k8] = *(const uint4*)(A + (size_t)(row0 + r) * 256 + k0 + k8);
            *(uint4*)&Bs[r * 72 + k8] = *(const uint4*)(Bw + (size_t)(col0 + r) * 256 + k0 + k8);
        }
        __syncthreads();
#pragma unroll
        for (int kc = 0; kc < 64; kc += 32) {
            v8s a[4], b[4];
#pragma unroll
            for (int mt = 0; mt < 4; ++mt)
                a[mt] = *(const v8s*)&As[(rh * 64 + mt * 16 + li) * 72 + kc + qd * 8];
#pragma unroll
            for (int nt = 0; nt < 4; ++nt)
                b[nt] = *(const v8s*)&Bs[(ch * 64 + nt * 16 + li) * 72 + kc + qd * 8];
#pragma unroll
            for (int mt = 0; mt < 4; ++mt)
#pragma unroll
                for (int nt = 0; nt < 4; ++nt)
                    acc[mt][nt] = __builtin_amdgcn_mfma_f32_16x16x32_bf16(a[mt], b[nt], acc[mt][nt], 0, 0, 0);
        }
        __syncthreads();
    }

    int reg3 = blockIdx.x >> 1;  // 0=q 1=k 2=v
    ushort* ob = (reg3 == 0) ? qo : (reg3 == 1) ? ko : vo;
    float sc = (reg3 == 0) ? 0.17677669529663687f : 1.0f;  // fold 1/sqrt(hd) into q
    int cb = (blockIdx.x & 1) * 128 + ch * 64;
#pragma unroll
    for (int mt = 0; mt < 4; ++mt)
#pragma unroll
        for (int nt = 0; nt < 4; ++nt) {
            int col = cb + nt * 16 + li;
            int hh = col >> 5, dd = col & 31;
#pragma unroll
            for (int r = 0; r < 4; ++r) {
                unsigned row = row0 + rh * 64 + mt * 16 + qd * 4 + r;
                unsigned bb = row / 300u;
                unsigned nn = row - bb * 300u;
                ob[(((size_t)bb * 8 + hh) * 300 + nn) * 32 + dd] = f2bf(acc[mt][nt][r] * sc);
            }
        }
}

// ---------------- K3: fused attention, rolled + software-pipelined ----------------
// S^T = mfma(A=K_tile, B=Q_tile): lane li = query row i, regs (qd*4+r) = key col j.
// Pipeline: iter n consumes s/v/gpl staged during iter n-1; next S-MFMA issues
// before current exp/PV; gpl (global, ~200cyc L2) prefetched 2 iters ahead.
__global__ __launch_bounds__(256, 2) void attn_mfma(
    const ushort* __restrict__ qg, const ushort* __restrict__ kg,
    const ushort* __restrict__ vg, const ushort* __restrict__ gpos,
    const float* __restrict__ gating, ushort* __restrict__ og)
{
    __shared__ ushort Ks[304 * 40];    // [seq][k] stride 40 (80B)
    __shared__ ushort Vt[32 * 328];    // [dim][seq] stride 328 (656B), seq 300..327 zero

    int bh = blockIdx.x, b = bh >> 3, h = bh & 7;
    int tid = threadIdx.x, wave = tid >> 6, lane = tid & 63, li = lane & 15, qd = lane >> 4;
    const ushort* kb = kg + (size_t)bh * 9600;
    const ushort* vb = vg + (size_t)bh * 9600;

    for (int c = tid; c < 1200; c += 256) {        // K: 300 rows x 4 u8-chunks
        int r = c >> 2, k8 = (c & 3) * 8;
        *(uint4*)&Ks[r * 40 + k8] = *(const uint4*)(kb + r * 32 + k8);
    }
    for (int c = tid; c < 2400; c += 256) {        // V transpose: 300 x 8 u4-chunks
        int sq = c >> 3, d4 = (c & 7) * 4;
        ushort4 t = *(const ushort4*)(vb + sq * 32 + d4);
        Vt[(d4 + 0) * 328 + sq] = t.x;
        Vt[(d4 + 1) * 328 + sq] = t.y;
        Vt[(d4 + 2) * 328 + sq] = t.z;
        Vt[(d4 + 3) * 328 + sq] = t.w;
    }
    for (int c = tid; c < 896; c += 256) {         // Vt seq pad 300..327 -> 0
        int d = c & 31, s = c >> 5;
        Vt[d * 328 + 300 + s] = 0;
    }
    float g = 1.f / (1.f + __expf(-gating[h]));
    float omg = 1.f - g;
    __syncthreads();

    const ushort* ksp0 = &Ks[li * 40 + qd * 8];
    const ushort* vtp0 = &Vt[li * 328 + qd * 4];
    const ushort* vtp1 = &Vt[(16 + li) * 328 + qd * 4];
    const v4f z4 = {0.f, 0.f, 0.f, 0.f};

    for (int rg = wave; rg < 19; rg += 4) {
        int i0 = rg * 16;
        // Q as B-operand: lane li holds Q row (i0+li); rows>=300 read into adjacent
        // k_bf region (valid memory, finite, masked at store)
        v8s bq = *(const v8s*)(qg + (size_t)bh * 9600 + (i0 + li) * 32 + qd * 8);
        const ushort* gp = gpos + ((size_t)h * 304 + (i0 + li)) * 304 + qd * 4;

        v4f Oe0 = z4, Oe1 = z4, Og0 = z4, Og1 = z4;
        float esum = 0.f;

        // ---- prologue: stage iter 0 (+ gpl for iter 1) ----
        uint2 gpl_a = *(const uint2*)(gp);             // nt=0
        uint2 gpl_b = *(const uint2*)(gp + 16);        // nt=1
        v8s ak = *(const v8s*)(ksp0);
        uint2 v0n = *(const uint2*)(vtp0);
        uint2 v1n = *(const uint2*)(vtp1);
        v4f s_next = __builtin_amdgcn_mfma_f32_16x16x32_bf16(ak, bq, z4, 0, 0, 0);

#pragma unroll 1
        for (int nt = 0; nt < 19; ++nt) {      // ROLLED (unrolled version spilled 57-119MB)
            v4f s = s_next;
            uint2 v0 = v0n, v1 = v1n;
            uint2 gpl = gpl_a;
            gpl_a = gpl_b;
            int ntp1 = (nt < 18) ? nt + 1 : 18;        // clamped (redundant last loads)
            int ntp2 = (nt < 17) ? nt + 2 : 18;
            gpl_b = *(const uint2*)(gp + ntp2 * 16);   // global: 2-deep prefetch
            ak = *(const v8s*)(ksp0 + ntp1 * 640);     // LDS: 1-deep prefetch
            v0n = *(const uint2*)(vtp0 + ntp1 * 16);
            v1n = *(const uint2*)(vtp1 + ntp1 * 16);
            s_next = __builtin_amdgcn_mfma_f32_16x16x32_bf16(ak, bq, z4, 0, 0, 0);

            float e0 = __expf(s[0]);               // scale folded into q
            float e1 = __expf(s[1]);
            float e2 = __expf(s[2]);
            float e3 = __expf(s[3]);
            if (nt == 18 && qd == 3) { e0 = e1 = e2 = e3 = 0.f; }  // j >= 300 (stale Ks rows)
            esum += (e0 + e1) + (e2 + e3);
            v8s ae = __builtin_bit_cast(v8s, (v4u){pk2bf(e0, e1), pk2bf(e2, e3), 0u, 0u});
            v8s ag = __builtin_bit_cast(v8s, (v4u){gpl.x, gpl.y, 0u, 0u});
            v8s b0 = __builtin_bit_cast(v8s, (v4u){v0.x, v0.y, 0u, 0u});
            v8s b1 = __builtin_bit_cast(v8s, (v4u){v1.x, v1.y, 0u, 0u});
            Oe0 = __builtin_amdgcn_mfma_f32_16x16x32_bf16(ae, b0, Oe0, 0, 0, 0);
            Oe1 = __builtin_amdgcn_mfma_f32_16x16x32_bf16(ae, b1, Oe1, 0, 0, 0);
            Og0 = __builtin_amdgcn_mfma_f32_16x16x32_bf16(ag, b0, Og0, 0, 0, 0);
            Og1 = __builtin_amdgcn_mfma_f32_16x16x32_bf16(ag, b1, Og1, 0, 0, 0);
        }
        esum += __shfl_xor(esum, 16);
        esum += __shfl_xor(esum, 32);              // full row sum for query i0+li
        float ps = omg / esum;                     // (skip /attn.sum: it's 1 +- 1e-6)
        // re-align ps (row i0+li) to C-layout rows (i0+qd*4+r)
        float psr[4];
#pragma unroll
        for (int r = 0; r < 4; ++r) psr[r] = __shfl(ps, qd * 4 + r);
#pragma unroll
        for (int r = 0; r < 4; ++r) {
            int row = i0 + qd * 4 + r;
            if (row < NSEQ) {
                size_t base = ((size_t)b * NSEQ + row) * 256 + h * 32 + li;
                og[base] = f2bf(fmaf(psr[r], Oe0[r], Og0[r]));
                og[base + 16] = f2bf(fmaf(psr[r], Oe1[r], Og1[r]));
            }
        }
    }
}

// ---------------- K4: output projection, BM=64, bf16 MFMA + fp32 bias ----------------
__global__ __launch_bounds__(256) void gemm_proj_mfma(
    const ushort* __restrict__ A, const ushort* __restrict__ Bw,
    const float* __restrict__ bias, float* __restrict__ out)
{
    __shared__ ushort As[64 * 72];    // 9.2 KB
    __shared__ ushort Bs[128 * 72];   // 18.4 KB
    int tid = threadIdx.x;
    int wave = tid >> 6, lane = tid & 63, li = lane & 15, qd = lane >> 4;
    int row0 = blockIdx.y * 64, col0 = blockIdx.x * 128;
    int rh = wave >> 1, ch = wave & 1;  // wave covers 32 rows x 64 cols

    v4f acc[2][4];
#pragma unroll
    for (int i = 0; i < 2; ++i)
#pragma unroll
        for (int j = 0; j < 4; ++j) acc[i][j] = (v4f){0.f, 0.f, 0.f, 0.f};

    for (int k0 = 0; k0 < 256; k0 += 64) {
#pragma unroll
        for (int s = 0; s < 2; ++s) {     // As: 64 rows x 8 chunks
            int c = s * 256 + tid;
            int r = c >> 3, k8 = (c & 7) * 8;
            *(uint4*)&As[r * 72 + k8] = *(const uint4*)(A + (size_t)(row0 + r) * 256 + k0 + k8);
        }
#pragma unroll
        for (int s = 0; s < 4; ++s) {     // Bs: 128 cols x 8 chunks
            int c = s * 256 + tid;
            int r = c >> 3, k8 = (c & 7) * 8;
            *(uint4*)&Bs[r * 72 + k8] = *(const uint4*)(Bw + (size_t)(col0 + r) * 256 + k0 + k8);
        }
        __syncthreads();
#pragma unroll
        for (int kc = 0; kc < 64; kc += 32) {
            v8s a[2], b[4];
#pragma unroll
            for (int mt = 0; mt < 2; ++mt)
                a[mt] = *(const v8s*)&As[(rh * 32 + mt * 16 + li) * 72 + kc + qd * 8];
#pragma unroll
            for (int nt = 0; nt < 4; ++nt)
                b[nt] = *(const v8s*)&Bs[(ch * 64 + nt * 16 + li) * 72 + kc + qd * 8];
#pragma unroll
            for (int mt = 0; mt < 2; ++mt)
#pragma unroll
                for (int nt = 0; nt < 4; ++nt)
                    acc[mt][nt] = __builtin_amdgcn_mfma_f32_16x16x32_bf16(a[mt], b[nt], acc[mt][nt], 0, 0, 0);
        }
        __syncthreads();
    }

#pragma unroll
    for (int mt = 0; mt < 2; ++mt)
#pragma unroll
        for (int nt = 0; nt < 4; ++nt) {
            int col = col0 + ch * 64 + nt * 16 + li;
            float bv = bias[col];
#pragma unroll
            for (int r = 0; r < 4; ++r) {
                int row = row0 + rh * 32 + mt * 16 + qd * 4 + r;
                out[(size_t)row * 256 + col] = acc[mt][nt][r] + bv;
            }
        }
}

extern "C" void kernel_launch(void* const* d_in, const int* in_sizes, int n_in,
                              void* d_out, int out_size, void* d_ws, size_t ws_size,
                              hipStream_t stream) {
    const float* x      = (const float*)d_in[0];
    const float* Wqk    = (const float*)d_in[1];
    const float* Wv     = (const float*)d_in[2];
    const float* Wpos   = (const float*)d_in[3];
    const float* bpos   = (const float*)d_in[4];
    const float* Wproj  = (const float*)d_in[5];
    const float* bproj  = (const float*)d_in[6];
    const float* gating = (const float*)d_in[7];
    float* out = (float*)d_out;

    ushort* gpos     = (ushort*)d_ws;             // 8*304*304 = 739,328
    ushort* x_bf     = gpos + 739328;             // 4,915,200
    ushort* wqkv_bf  = x_bf + 4915200;            // 196,608 (Wqk 0..511, Wv 512..767)
    ushort* wproj_bf = wqkv_bf + 196608;          // 65,536
    ushort* q_bf     = wproj_bf + 65536;          // 4,915,200 each
    ushort* k_bf     = q_bf + 4915200;
    ushort* v_bf     = k_bf + 4915200;
    ushort* o_bf     = v_bf + 4915200;

    prep_kernel<<<5664, 256, 0, stream>>>(x, Wqk, Wv, Wproj, Wpos, bpos, gating,
                                          x_bf, wqkv_bf, wproj_bf, gpos);
    gemm_qkv_mfma<<<dim3(6, 150), 256, 0, stream>>>(x_bf, wqkv_bf, q_bf, k_bf, v_bf);
    attn_mfma<<<dim3(64 * HEADS), 256, 0, stream>>>(q_bf, k_bf, v_bf, gpos, gating, o_bf);
    gemm_proj_mfma<<<dim3(2, 300), 256, 0, stream>>>(o_bf, wproj_bf, bproj, out);
}

// Round 8
// 154.439 us; speedup vs baseline: 1.5019x; 1.0355x over previous
//
#include <hip/hip_runtime.h>

// GPSA bf16-MFMA v8. B=64, N=300, C=256, H=8, hd=32.
// K0 prep: x/Wqk|Wv/Wproj -> bf16 in TILED+SWIZZLED layout [tile][kt][128][64]
//          (chunk slot c^(row&7)); gpos[h,i,j] = bf16(g_h*softmax_j(...)) [8,304,304]
// K2 gemm_qkv_mfma: m97-style: global_load_lds width=16 straight DMA into LDS
//          (layout pre-swizzled in global -> no pads needed, 2-way banks max),
//          2-barrier K-loop. q pre-scaled by 1/sqrt(32). out [B,H,300,32].
// K3 attn_mfma: r7 pipelined register-P loop, occupancy 2->3 blocks/CU;
//          epilogue writes o in tiled+swizzled layout for proj's DMA.
// K4 gemm_proj_mfma: same m97 structure, BM=64 (600 blocks), + bias -> fp32 out.

#define NSEQ 300
#define HEADS 8
#define HD 32

typedef short v8s __attribute__((ext_vector_type(8)));
typedef float v4f __attribute__((ext_vector_type(4)));
typedef unsigned int v4u __attribute__((ext_vector_type(4)));

__device__ __forceinline__ ushort f2bf(float f) {
    unsigned u = __float_as_uint(f);
    u = (u + 0x7FFFu + ((u >> 16) & 1u)) >> 16;   // RNE
    return (ushort)u;
}

// pack two fp32 -> packed bf16x2 (lo=a, hi=b) via v_perm
__device__ __forceinline__ unsigned pk2bf(float a, float b) {
    unsigned ua = __float_as_uint(a), ub = __float_as_uint(b);
    ua += 0x7FFFu + ((ua >> 16) & 1u);
    ub += 0x7FFFu + ((ub >> 16) & 1u);
    return __builtin_amdgcn_perm(ub, ua, 0x07060302);  // [ua.hi16 | ub.hi16]
}

// async global->LDS DMA, 16B per lane (wave-uniform base + lane*16; both ptrs
// computed so per-lane global and LDS addresses advance together by 16B)
__device__ __forceinline__ void gl_lds16(const ushort* g, ushort* l) {
    __builtin_amdgcn_global_load_lds(
        (const __attribute__((address_space(1))) void*)g,
        (__attribute__((address_space(3))) void*)l, 16, 0, 0);
}

// ---------------- K0: prep = convert+tile+swizzle + gated positional softmax ----------------
// blocks 0..2399: x (614400 chunk-threads) | 2400..2495: Wqk|Wv | 2496..2527: Wproj
// blocks 2528..3135: gpos rows (608 blocks x 4 rows x 64 lanes)
__global__ __launch_bounds__(256) void prep_kernel(
    const float* __restrict__ x, const float* __restrict__ Wqk,
    const float* __restrict__ Wv, const float* __restrict__ Wproj,
    const float* __restrict__ Wpos, const float* __restrict__ bpos,
    const float* __restrict__ gating,
    ushort* __restrict__ x_t, ushort* __restrict__ wqkv_t,
    ushort* __restrict__ wproj_t, ushort* __restrict__ gpos)
{
    int bid = blockIdx.x, tid = threadIdx.x;
    if (bid < 2528) {
        const float* src; ushort* dstbase; int m, ck;
        if (bid < 2400) {                         // x: 19200 rows x 32 chunks
            int idx = bid * 256 + tid;
            m = idx >> 5; ck = idx & 31;
            src = x + (size_t)m * 256 + ck * 8;
            dstbase = x_t;
        } else if (bid < 2496) {                  // W qkv: 768 rows x 32 chunks
            int idx = (bid - 2400) * 256 + tid;
            m = idx >> 5; ck = idx & 31;
            src = (m < 512 ? Wqk + (size_t)m * 256 : Wv + (size_t)(m - 512) * 256) + ck * 8;
            dstbase = wqkv_t;
        } else {                                  // W proj: 256 rows x 32 chunks
            int idx = (bid - 2496) * 256 + tid;
            m = idx >> 5; ck = idx & 31;
            src = Wproj + (size_t)m * 256 + ck * 8;
            dstbase = wproj_t;
        }
        int rt = m >> 7, rr = m & 127, kt = ck >> 3, c = ck & 7;
        float4 f0 = *(const float4*)src;
        float4 f1 = *(const float4*)(src + 4);
        v4u pk = {pk2bf(f0.x, f0.y), pk2bf(f0.z, f0.w),
                  pk2bf(f1.x, f1.y), pk2bf(f1.z, f1.w)};
        // tiled layout [rt][kt][128 rows][8 chunks], chunk slot swizzled by row&7
        *(v4u*)(dstbase + ((size_t)(rt * 4 + kt) * 128 + rr) * 64 + ((c ^ (rr & 7)) * 8)) = pk;
        return;
    }
    int sub = bid - 2528;                       // 0..607
    int h = sub / 76;
    int i = (sub % 76) * 4 + (tid >> 6);        // row 0..303
    int lane = tid & 63;
    ushort* gr = gpos + ((size_t)h * 304 + i) * 304;
    if (i >= NSEQ) {
#pragma unroll
        for (int t = 0; t < 5; ++t) {
            int j = lane + 64 * t;
            if (j < 304) gr[j] = 0;
        }
        return;
    }
    float w0 = Wpos[h * 3 + 0], w2 = Wpos[h * 3 + 2], bb = bpos[h];
    float g = 1.f / (1.f + __expf(-gating[h]));
    float sv[5]; float m2 = -1e30f;
#pragma unroll
    for (int t = 0; t < 5; ++t) {
        int j = lane + 64 * t;
        float d = (float)(j - i);
        float lg = fmaf(w2, d * d, fmaf(w0, d, bb));
        sv[t] = (j < NSEQ) ? lg : -1e30f;       // logits +-7000: max-sub required
        m2 = fmaxf(m2, sv[t]);
    }
#pragma unroll
    for (int off = 32; off > 0; off >>= 1) m2 = fmaxf(m2, __shfl_xor(m2, off));
    float sum = 0.f;
#pragma unroll
    for (int t = 0; t < 5; ++t) { sv[t] = __expf(sv[t] - m2); sum += sv[t]; }
#pragma unroll
    for (int off = 32; off > 0; off >>= 1) sum += __shfl_xor(sum, off);
    float gi = g / sum;
#pragma unroll
    for (int t = 0; t < 5; ++t) {
        int j = lane + 64 * t;
        if (j < NSEQ) gr[j] = f2bf(sv[t] * gi);
        else if (j < 304) gr[j] = 0;
    }
}

// ---------------- K2: QKV GEMM, global_load_lds DMA + swizzled LDS ----------------
__global__ __launch_bounds__(256, 4) void gemm_qkv_mfma(
    const ushort* __restrict__ A, const ushort* __restrict__ Bw,
    ushort* __restrict__ qo, ushort* __restrict__ ko, ushort* __restrict__ vo)
{
    __shared__ ushort As[128 * 64];   // straight DMA copies of pre-swizzled tiles
    __shared__ ushort Bs[128 * 64];
    int tid = threadIdx.x;
    int wave = tid >> 6, lane = tid & 63, li = lane & 15, qd = lane >> 4;
    int rh = wave >> 1, ch = wave & 1;
    const ushort* gA = A + (size_t)blockIdx.y * 4 * 8192;
    const ushort* gB = Bw + (size_t)blockIdx.x * 4 * 8192;

    v4f acc[4][4];
#pragma unroll
    for (int i = 0; i < 4; ++i)
#pragma unroll
        for (int j = 0; j < 4; ++j) acc[i][j] = (v4f){0.f, 0.f, 0.f, 0.f};

    for (int kt = 0; kt < 4; ++kt) {
#pragma unroll
        for (int s = 0; s < 4; ++s) {
            int cch = s * 256 + tid;          // 1024 chunks of 16B per tile
            gl_lds16(gA + (size_t)kt * 8192 + cch * 8, As + cch * 8);
            gl_lds16(gB + (size_t)kt * 8192 + cch * 8, Bs + cch * 8);
        }
        __syncthreads();                      // drains vmcnt (DMA) per barrier semantics
#pragma unroll
        for (int kc = 0; kc < 64; kc += 32) {
            int cb = (kc >> 3) + qd;          // logical chunk for k = kc + qd*8
            int cs = cb ^ (li & 7);           // swizzled slot (row&7 == li&7 here)
            v8s a[4], b[4];
#pragma unroll
            for (int mt = 0; mt < 4; ++mt)
                a[mt] = *(const v8s*)&As[(rh * 64 + mt * 16 + li) * 64 + cs * 8];
#pragma unroll
            for (int nt = 0; nt < 4; ++nt)
                b[nt] = *(const v8s*)&Bs[(ch * 64 + nt * 16 + li) * 64 + cs * 8];
#pragma unroll
            for (int mt = 0; mt < 4; ++mt)
#pragma unroll
                for (int nt = 0; nt < 4; ++nt)
                    acc[mt][nt] = __builtin_amdgcn_mfma_f32_16x16x32_bf16(a[mt], b[nt], acc[mt][nt], 0, 0, 0);
        }
        __syncthreads();
    }

    int reg3 = blockIdx.x >> 1;  // 0=q 1=k 2=v
    ushort* ob = (reg3 == 0) ? qo : (reg3 == 1) ? ko : vo;
    float sc = (reg3 == 0) ? 0.17677669529663687f : 1.0f;  // fold 1/sqrt(hd) into q
    int cb2 = (blockIdx.x & 1) * 128 + ch * 64;
#pragma unroll
    for (int mt = 0; mt < 4; ++mt)
#pragma unroll
        for (int nt = 0; nt < 4; ++nt) {
            int col = cb2 + nt * 16 + li;
            int hh = col >> 5, dd = col & 31;
#pragma unroll
            for (int r = 0; r < 4; ++r) {
                unsigned row = blockIdx.y * 128 + rh * 64 + mt * 16 + qd * 4 + r;
                unsigned bb = row / 300u;
                unsigned nn = row - bb * 300u;
                ob[(((size_t)bb * 8 + hh) * 300 + nn) * 32 + dd] = f2bf(acc[mt][nt][r] * sc);
            }
        }
}

// ---------------- K3: fused attention, rolled + pipelined, 3 blocks/CU ----------------
__global__ __launch_bounds__(256, 3) void attn_mfma(
    const ushort* __restrict__ qg, const ushort* __restrict__ kg,
    const ushort* __restrict__ vg, const ushort* __restrict__ gpos,
    const float* __restrict__ gating, ushort* __restrict__ ot)
{
    __shared__ ushort Ks[304 * 40];    // [seq][k] stride 40 (80B)
    __shared__ ushort Vt[32 * 328];    // [dim][seq] stride 328, seq 300..327 zero

    int bh = blockIdx.x, b = bh >> 3, h = bh & 7;
    int tid = threadIdx.x, wave = tid >> 6, lane = tid & 63, li = lane & 15, qd = lane >> 4;
    const ushort* kb = kg + (size_t)bh * 9600;
    const ushort* vb = vg + (size_t)bh * 9600;

    for (int c = tid; c < 1200; c += 256) {        // K: 300 rows x 4 u8-chunks
        int r = c >> 2, k8 = (c & 3) * 8;
        *(uint4*)&Ks[r * 40 + k8] = *(const uint4*)(kb + r * 32 + k8);
    }
    for (int c = tid; c < 2400; c += 256) {        // V transpose: 300 x 8 u4-chunks
        int sq = c >> 3, d4 = (c & 7) * 4;
        ushort4 t = *(const ushort4*)(vb + sq * 32 + d4);
        Vt[(d4 + 0) * 328 + sq] = t.x;
        Vt[(d4 + 1) * 328 + sq] = t.y;
        Vt[(d4 + 2) * 328 + sq] = t.z;
        Vt[(d4 + 3) * 328 + sq] = t.w;
    }
    for (int c = tid; c < 896; c += 256) {         // Vt seq pad 300..327 -> 0
        int d = c & 31, s = c >> 5;
        Vt[d * 328 + 300 + s] = 0;
    }
    float g = 1.f / (1.f + __expf(-gating[h]));
    float omg = 1.f - g;
    __syncthreads();

    const ushort* ksp0 = &Ks[li * 40 + qd * 8];
    const ushort* vtp0 = &Vt[li * 328 + qd * 4];
    const ushort* vtp1 = &Vt[(16 + li) * 328 + qd * 4];
    const v4f z4 = {0.f, 0.f, 0.f, 0.f};

    for (int rg = wave; rg < 19; rg += 4) {
        int i0 = rg * 16;
        // Q as B-operand: lane li holds Q row (i0+li); rows>=300 read into adjacent
        // k_bf region (valid memory, finite, masked at store)
        v8s bq = *(const v8s*)(qg + (size_t)bh * 9600 + (i0 + li) * 32 + qd * 8);
        const ushort* gp = gpos + ((size_t)h * 304 + (i0 + li)) * 304 + qd * 4;

        v4f Oe0 = z4, Oe1 = z4, Og0 = z4, Og1 = z4;
        float esum = 0.f;

        // prologue: stage iter 0 (+ gpl for iter 1)
        uint2 gpl_a = *(const uint2*)(gp);
        uint2 gpl_b = *(const uint2*)(gp + 16);
        v8s ak = *(const v8s*)(ksp0);
        uint2 v0n = *(const uint2*)(vtp0);
        uint2 v1n = *(const uint2*)(vtp1);
        v4f s_next = __builtin_amdgcn_mfma_f32_16x16x32_bf16(ak, bq, z4, 0, 0, 0);

#pragma unroll 1
        for (int nt = 0; nt < 19; ++nt) {      // ROLLED (unrolled spilled 57-119MB)
            v4f s = s_next;
            uint2 v0 = v0n, v1 = v1n;
            uint2 gpl = gpl_a;
            gpl_a = gpl_b;
            int ntp1 = (nt < 18) ? nt + 1 : 18;
            int ntp2 = (nt < 17) ? nt + 2 : 18;
            gpl_b = *(const uint2*)(gp + ntp2 * 16);   // global: 2-deep prefetch
            ak = *(const v8s*)(ksp0 + ntp1 * 640);     // LDS: 1-deep prefetch
            v0n = *(const uint2*)(vtp0 + ntp1 * 16);
            v1n = *(const uint2*)(vtp1 + ntp1 * 16);
            s_next = __builtin_amdgcn_mfma_f32_16x16x32_bf16(ak, bq, z4, 0, 0, 0);

            float e0 = __expf(s[0]);               // scale folded into q
            float e1 = __expf(s[1]);
            float e2 = __expf(s[2]);
            float e3 = __expf(s[3]);
            if (nt == 18 && qd == 3) { e0 = e1 = e2 = e3 = 0.f; }  // j >= 300
            esum += (e0 + e1) + (e2 + e3);
            v8s ae = __builtin_bit_cast(v8s, (v4u){pk2bf(e0, e1), pk2bf(e2, e3), 0u, 0u});
            v8s ag = __builtin_bit_cast(v8s, (v4u){gpl.x, gpl.y, 0u, 0u});
            v8s b0 = __builtin_bit_cast(v8s, (v4u){v0.x, v0.y, 0u, 0u});
            v8s b1 = __builtin_bit_cast(v8s, (v4u){v1.x, v1.y, 0u, 0u});
            Oe0 = __builtin_amdgcn_mfma_f32_16x16x32_bf16(ae, b0, Oe0, 0, 0, 0);
            Oe1 = __builtin_amdgcn_mfma_f32_16x16x32_bf16(ae, b1, Oe1, 0, 0, 0);
            Og0 = __builtin_amdgcn_mfma_f32_16x16x32_bf16(ag, b0, Og0, 0, 0, 0);
            Og1 = __builtin_amdgcn_mfma_f32_16x16x32_bf16(ag, b1, Og1, 0, 0, 0);
        }
        esum += __shfl_xor(esum, 16);
        esum += __shfl_xor(esum, 32);              // full row sum for query i0+li
        float ps = omg / esum;                     // (skip /attn.sum: it's 1 +- 1e-6)
        float psr[4];
#pragma unroll
        for (int r = 0; r < 4; ++r) psr[r] = __shfl(ps, qd * 4 + r);
        // store o in tiled+swizzled layout for proj's DMA:
        // k-col = h*32+li (O0) / +16 (O1): kt = h>>1, chunk c0 = (h&1)*4 + li>>3
#pragma unroll
        for (int r = 0; r < 4; ++r) {
            int row = i0 + qd * 4 + r;
            if (row < NSEQ) {
                int m = b * NSEQ + row;
                int rt = m >> 7, rr = m & 127;
                int c0 = (h & 1) * 4 + (li >> 3);
                int p = li & 7;
                size_t tb = ((size_t)(rt * 4 + (h >> 1)) * 128 + rr) * 64;
                ot[tb + ((c0 ^ (rr & 7)) * 8) + p] = f2bf(fmaf(psr[r], Oe0[r], Og0[r]));
                ot[tb + (((c0 + 2) ^ (rr & 7)) * 8) + p] = f2bf(fmaf(psr[r], Oe1[r], Og1[r]));
            }
        }
    }
}

// ---------------- K4: output projection, BM=64, DMA staging + bias ----------------
__global__ __launch_bounds__(256, 4) void gemm_proj_mfma(
    const ushort* __restrict__ A, const ushort* __restrict__ Bw,
    const float* __restrict__ bias, float* __restrict__ out)
{
    __shared__ ushort As[64 * 64];    // 8 KB
    __shared__ ushort Bs[128 * 64];   // 16 KB
    int tid = threadIdx.x;
    int wave = tid >> 6, lane = tid & 63, li = lane & 15, qd = lane >> 4;
    int rh = wave >> 1, ch = wave & 1;  // wave: 32 rows x 64 cols
    int by = blockIdx.y;
    // A rows by*64..+63 = half of 128-row tile rt = by>>1 (contiguous in tile)
    const ushort* gA = A + ((size_t)(by >> 1) * 4 * 128 + (by & 1) * 64) * 64;
    const ushort* gB = Bw + (size_t)blockIdx.x * 4 * 8192;

    v4f acc[2][4];
#pragma unroll
    for (int i = 0; i < 2; ++i)
#pragma unroll
        for (int j = 0; j < 4; ++j) acc[i][j] = (v4f){0.f, 0.f, 0.f, 0.f};

    for (int kt = 0; kt < 4; ++kt) {
#pragma unroll
        for (int s = 0; s < 2; ++s) {     // As: 512 chunks
            int cch = s * 256 + tid;
            gl_lds16(gA + (size_t)kt * 128 * 64 + cch * 8, As + cch * 8);
        }
#pragma unroll
        for (int s = 0; s < 4; ++s) {     // Bs: 1024 chunks
            int cch = s * 256 + tid;
            gl_lds16(gB + (size_t)kt * 8192 + cch * 8, Bs + cch * 8);
        }
        __syncthreads();
#pragma unroll
        for (int kc = 0; kc < 64; kc += 32) {
            int cb = (kc >> 3) + qd;
            int cs = cb ^ (li & 7);
            v8s a[2], b[4];
#pragma unroll
            for (int mt = 0; mt < 2; ++mt)
                a[mt] = *(const v8s*)&As[(rh * 32 + mt * 16 + li) * 64 + cs * 8];
#pragma unroll
            for (int nt = 0; nt < 4; ++nt)
                b[nt] = *(const v8s*)&Bs[(ch * 64 + nt * 16 + li) * 64 + cs * 8];
#pragma unroll
            for (int mt = 0; mt < 2; ++mt)
#pragma unroll
                for (int nt = 0; nt < 4; ++nt)
                    acc[mt][nt] = __builtin_amdgcn_mfma_f32_16x16x32_bf16(a[mt], b[nt], acc[mt][nt], 0, 0, 0);
        }
        __syncthreads();
    }

#pragma unroll
    for (int mt = 0; mt < 2; ++mt)
#pragma unroll
        for (int nt = 0; nt < 4; ++nt) {
            int col = blockIdx.x * 128 + ch * 64 + nt * 16 + li;
            float bv = bias[col];
#pragma unroll
            for (int r = 0; r < 4; ++r) {
                int row = by * 64 + rh * 32 + mt * 16 + qd * 4 + r;
                out[(size_t)row * 256 + col] = acc[mt][nt][r] + bv;
            }
        }
}

extern "C" void kernel_launch(void* const* d_in, const int* in_sizes, int n_in,
                              void* d_out, int out_size, void* d_ws, size_t ws_size,
                              hipStream_t stream) {
    const float* x      = (const float*)d_in[0];
    const float* Wqk    = (const float*)d_in[1];
    const float* Wv     = (const float*)d_in[2];
    const float* Wpos   = (const float*)d_in[3];
    const float* bpos   = (const float*)d_in[4];
    const float* Wproj  = (const float*)d_in[5];
    const float* bproj  = (const float*)d_in[6];
    const float* gating = (const float*)d_in[7];
    float* out = (float*)d_out;

    ushort* gpos     = (ushort*)d_ws;             // 8*304*304 = 739,328
    ushort* x_t      = gpos + 739328;             // 4,915,200 (tiled+swizzled)
    ushort* wqkv_t   = x_t + 4915200;             // 196,608  (tiled+swizzled)
    ushort* wproj_t  = wqkv_t + 196608;           // 65,536   (tiled+swizzled)
    ushort* q_bf     = wproj_t + 65536;           // 4,915,200 each, [B,H,300,32]
    ushort* k_bf     = q_bf + 4915200;
    ushort* v_bf     = k_bf + 4915200;
    ushort* o_t      = v_bf + 4915200;            // 4,915,200 (tiled+swizzled)

    prep_kernel<<<3136, 256, 0, stream>>>(x, Wqk, Wv, Wproj, Wpos, bpos, gating,
                                          x_t, wqkv_t, wproj_t, gpos);
    gemm_qkv_mfma<<<dim3(6, 150), 256, 0, stream>>>(x_t, wqkv_t, q_bf, k_bf, v_bf);
    attn_mfma<<<dim3(64 * HEADS), 256, 0, stream>>>(q_bf, k_bf, v_bf, gpos, gating, o_t);
    gemm_proj_mfma<<<dim3(2, 300), 256, 0, stream>>>(o_t, wproj_t, bproj, out);
}